// Round 2
// baseline (35168.646 us; speedup 1.0000x reference)
//
#include <hip/hip_runtime.h>
#include <hip/hip_bf16.h>

typedef _Float16 f16;
typedef f16  f16x8 __attribute__((ext_vector_type(8)));
typedef float f32x4 __attribute__((ext_vector_type(4)));

__device__ __forceinline__ f16x8 ld8h(const f16* p) {
    return *reinterpret_cast<const f16x8*>(p);
}
__device__ __forceinline__ void fsplit(float x, f16* hi, f16* lo) {
    f16 h = (f16)x;
    *hi = h;
    *lo = (f16)((x - (float)h) * 4096.0f);
}

// ---------------- element counts ----------------
constexpr size_t NXE     = 128ull*256*128;
constexpr size_t NPM     = 1024ull*4096;
constexpr size_t NWIH0   = 3072ull*384;
constexpr size_t NWIH12  = 3072ull*256;
constexpr size_t NWIH3   = 3456ull*256;
constexpr size_t NWHH012 = 3072ull*1024;
constexpr size_t NWHH3   = 3456ull*1152;
constexpr size_t NCEN    = 128ull*4096;
constexpr size_t NCTX    = 128ull*1024;
constexpr size_t NH012   = 128ull*1024;
constexpr size_t NH3     = 128ull*1152;
constexpr size_t NG      = 128ull*12672;

// ---------------- workspace offsets (bytes) ----------------
constexpr size_t OFF_XH   = 0;
constexpr size_t OFF_XL   = OFF_XH + NXE*2;
constexpr size_t OFF_PMH  = OFF_XL + NXE*2;
constexpr size_t OFF_PML  = OFF_PMH + NPM*2;
constexpr size_t OFF_WIHH0= OFF_PML + NPM*2;
constexpr size_t OFF_WIHH1= OFF_WIHH0 + NWIH0*2;
constexpr size_t OFF_WIHH2= OFF_WIHH1 + NWIH12*2;
constexpr size_t OFF_WIHH3= OFF_WIHH2 + NWIH12*2;
constexpr size_t OFF_WIHL0= OFF_WIHH3 + NWIH3*2;
constexpr size_t OFF_WIHL1= OFF_WIHL0 + NWIH0*2;
constexpr size_t OFF_WIHL2= OFF_WIHL1 + NWIH12*2;
constexpr size_t OFF_WIHL3= OFF_WIHL2 + NWIH12*2;
constexpr size_t OFF_WHHH0= OFF_WIHL3 + NWIH3*2;
constexpr size_t OFF_WHHH1= OFF_WHHH0 + NWHH012*2;
constexpr size_t OFF_WHHH2= OFF_WHHH1 + NWHH012*2;
constexpr size_t OFF_WHHH3= OFF_WHHH2 + NWHH012*2;
constexpr size_t OFF_WHHL0= OFF_WHHH3 + NWHH3*2;
constexpr size_t OFF_WHHL1= OFF_WHHL0 + NWHH012*2;
constexpr size_t OFF_WHHL2= OFF_WHHL1 + NWHH012*2;
constexpr size_t OFF_WHHL3= OFF_WHHL2 + NWHH012*2;
constexpr size_t OFF_CENH = OFF_WHHL3 + NWHH3*2;
constexpr size_t OFF_CENL = OFF_CENH + NCEN*2;
constexpr size_t OFF_CTXH = OFF_CENL + NCEN*2;
constexpr size_t OFF_CTXL = OFF_CTXH + NCTX*2;
constexpr size_t OFF_HH0  = OFF_CTXL + NCTX*2;
constexpr size_t OFF_HH1  = OFF_HH0 + NH012*2;
constexpr size_t OFF_HH2  = OFF_HH1 + NH012*2;
constexpr size_t OFF_HH3  = OFF_HH2 + NH012*2;
constexpr size_t OFF_HL0  = OFF_HH3 + NH3*2;
constexpr size_t OFF_HL1  = OFF_HL0 + NH012*2;
constexpr size_t OFF_HL2  = OFF_HL1 + NH012*2;
constexpr size_t OFF_HL3  = OFF_HL2 + NH012*2;
constexpr size_t OFF_HF0  = OFF_HL3 + NH3*2;
constexpr size_t OFF_HF1  = OFF_HF0 + NH012*4;
constexpr size_t OFF_HF2  = OFF_HF1 + NH012*4;
constexpr size_t OFF_HF3  = OFF_HF2 + NH012*4;
constexpr size_t OFF_G1   = OFF_HF3 + NH3*4;
constexpr size_t OFF_G2   = OFF_G1 + NG*4;
constexpr size_t WS_NEED  = OFF_G2 + NG*4;   // ~122 MB

__device__ __forceinline__ size_t moff_g(int i) {
    return i==0 ? 0 : i==1 ? 393216 : i==2 ? 786432 : 1179648;
}

// ---------------- prep kernels ----------------
__global__ void k_split_n(const float* __restrict__ s, f16* __restrict__ hi,
                          f16* __restrict__ lo, int n) {
    int g = blockIdx.x*256 + threadIdx.x;
    if (g < n) fsplit(s[g], &hi[g], &lo[g]);
}

__global__ void k_pmt_split(const float* __restrict__ p0, const float* __restrict__ p1,
                            const float* __restrict__ p2, const float* __restrict__ p3,
                            f16* __restrict__ pmh, f16* __restrict__ pml) {
    int g = blockIdx.x*256 + threadIdx.x;   // over 1024*4096
    if (g >= (int)NPM) return;
    int ngl = g >> 12;         // global col 0..1023
    int k   = g & 4095;
    int i   = ngl >> 8;
    int n   = ngl & 255;
    const float* p = (i==0?p0 : i==1?p1 : i==2?p2 : p3);
    fsplit(p[(size_t)k*256 + n], &pmh[g], &pml[g]);
}

__global__ void k_init_cen(const float* __restrict__ ci, char* ws) {
    int g = blockIdx.x*256 + threadIdx.x;   // 4*128*1024
    if (g >= 4*128*1024) return;
    int i = g >> 17;
    int rem = g & 131071;
    int b = rem >> 10, c = rem & 1023;
    size_t idx = (size_t)b*4096 + i*1024 + c;
    fsplit(ci[g], (f16*)(ws + OFF_CENH) + idx, (f16*)(ws + OFF_CENL) + idx);
}

__global__ void k_init_mod(const float* __restrict__ mi, char* ws) {
    int g = blockIdx.x*256 + threadIdx.x;   // 3*128*1024
    if (g >= 3*128*1024) return;
    int i = g >> 17; int rem = g & 131071;
    float v = mi[g];
    float* hf = (float*)(ws + (i==0?OFF_HF0 : i==1?OFF_HF1 : OFF_HF2));
    f16* hh = (f16*)(ws + (i==0?OFF_HH0 : i==1?OFF_HH1 : OFF_HH2));
    f16* hl = (f16*)(ws + (i==0?OFF_HL0 : i==1?OFF_HL1 : OFF_HL2));
    hf[rem] = v;
    fsplit(v, &hh[rem], &hl[rem]);
}

__global__ void k_init_last(const float* __restrict__ ml, char* ws) {
    int g = blockIdx.x*256 + threadIdx.x;   // 128*1152
    if (g >= 128*1152) return;
    float v = ml[g];
    ((float*)(ws + OFF_HF3))[g] = v;
    fsplit(v, (f16*)(ws + OFF_HH3) + g, (f16*)(ws + OFF_HL3) + g);
}

// ---------------- step kernel 1: ctx = center @ pm ----------------
// 256 blocks: 8 m-tiles(16) x 32 n-tiles(32); 4 waves split K=4096 into 1024 each,
// deterministic LDS reduction (fixed order).
__global__ __launch_bounds__(256) void k_ctx(char* ws) {
    __shared__ float red[4*512];
    const f16* cenh = (const f16*)(ws + OFF_CENH);
    const f16* cenl = (const f16*)(ws + OFF_CENL);
    const f16* pmh  = (const f16*)(ws + OFF_PMH);
    const f16* pml  = (const f16*)(ws + OFF_PML);
    f16* ctxh = (f16*)(ws + OFF_CTXH);
    f16* ctxl = (f16*)(ws + OFF_CTXL);

    int tid = threadIdx.x, lane = tid & 63, wv = tid >> 6;
    int bm = blockIdx.x & 7, bn = blockIdx.x >> 3;
    int m0 = bm*16, n0 = bn*32;
    int k0 = wv*1024;
    int kb = (lane >> 4)*8;
    int fr = lane & 15;   // A-row / B-col / D-col index within fragment

    const f16* Ah  = cenh + (size_t)(m0 + fr)*4096 + k0 + kb;
    const f16* Al  = cenl + (size_t)(m0 + fr)*4096 + k0 + kb;
    const f16* Bh0 = pmh + (size_t)(n0 + fr)*4096 + k0 + kb;
    const f16* Bh1 = Bh0 + 16*4096;
    const f16* Bl0 = pml + (size_t)(n0 + fr)*4096 + k0 + kb;
    const f16* Bl1 = Bl0 + 16*4096;

    f32x4 hh0 = {0,0,0,0}, hh1 = {0,0,0,0}, cr0 = {0,0,0,0}, cr1 = {0,0,0,0};
    for (int k = 0; k < 1024; k += 32) {
        f16x8 ah = ld8h(Ah + k), al = ld8h(Al + k);
        f16x8 b0 = ld8h(Bh0 + k), b1 = ld8h(Bh1 + k);
        hh0 = __builtin_amdgcn_mfma_f32_16x16x32_f16(ah, b0, hh0, 0, 0, 0);
        hh1 = __builtin_amdgcn_mfma_f32_16x16x32_f16(ah, b1, hh1, 0, 0, 0);
        cr0 = __builtin_amdgcn_mfma_f32_16x16x32_f16(al, b0, cr0, 0, 0, 0);
        cr1 = __builtin_amdgcn_mfma_f32_16x16x32_f16(al, b1, cr1, 0, 0, 0);
    }
    for (int k = 0; k < 1024; k += 32) {
        f16x8 ah = ld8h(Ah + k);
        f16x8 b0 = ld8h(Bl0 + k), b1 = ld8h(Bl1 + k);
        cr0 = __builtin_amdgcn_mfma_f32_16x16x32_f16(ah, b0, cr0, 0, 0, 0);
        cr1 = __builtin_amdgcn_mfma_f32_16x16x32_f16(ah, b1, cr1, 0, 0, 0);
    }
    #pragma unroll
    for (int rr = 0; rr < 4; ++rr) {
        int r4 = (lane >> 4)*4 + rr;
        red[wv*512 + 0*256 + r4*16 + fr] = hh0[rr] + cr0[rr]*(1.0f/4096.0f);
        red[wv*512 + 1*256 + r4*16 + fr] = hh1[rr] + cr1[rr]*(1.0f/4096.0f);
    }
    __syncthreads();
    for (int o = tid; o < 512; o += 256) {
        float s = red[o] + red[512 + o] + red[1024 + o] + red[1536 + o];
        int f = o >> 8, rem = o & 255, r = rem >> 4, c = rem & 15;
        size_t idx = (size_t)(m0 + r)*1024 + n0 + f*16 + c;
        fsplit(s, &ctxh[idx], &ctxl[idx]);
    }
}

// ---------------- step kernel 2: all gate GEMMs (fp16 3-term split) ----------------
// 792 blocks: [0,396) G1, [396,792) G2; per-module col-tiles of 32.
// Block: 128 rows x 32 cols; wave = 32 rows (2 m-frags) x 32 cols (2 n-frags).
__global__ __launch_bounds__(256) void k_gates(char* ws, int t) {
    int tid = threadIdx.x, lane = tid & 63, wv = tid >> 6;
    int bid = blockIdx.x;
    bool isG2 = bid >= 396;
    int r = isG2 ? bid - 396 : bid;
    int i, nt;
    if (r < 96)       { i = 0; nt = r; }
    else if (r < 192) { i = 1; nt = r - 96; }
    else if (r < 288) { i = 2; nt = r - 192; }
    else              { i = 3; nt = r - 288; }
    const int N3 = (i == 3) ? 3456 : 3072;
    const int K  = isG2 ? ((i == 3) ? 1152 : 1024) : ((i == 0) ? 384 : 256);
    const f16* Wh = (const f16*)(ws + (isG2
        ? (i==0?OFF_WHHH0 : i==1?OFF_WHHH1 : i==2?OFF_WHHH2 : OFF_WHHH3)
        : (i==0?OFF_WIHH0 : i==1?OFF_WIHH1 : i==2?OFF_WIHH2 : OFF_WIHH3)));
    const f16* Wl = (const f16*)(ws + (isG2
        ? (i==0?OFF_WHHL0 : i==1?OFF_WHHL1 : i==2?OFF_WHHL2 : OFF_WHHL3)
        : (i==0?OFF_WIHL0 : i==1?OFF_WIHL1 : i==2?OFF_WIHL2 : OFF_WIHL3)));
    float* Gout = (float*)(ws + (isG2 ? OFF_G2 : OFF_G1)) + moff_g(i);

    int kb = (lane >> 4) * 8;
    int fr = lane & 15;
    int m0 = wv*32 + fr;
    int m1 = m0 + 16;
    int n0 = nt * 32;

    const f16* Bh0 = Wh + (size_t)(n0 + fr)*K + kb;
    const f16* Bh1 = Bh0 + 16*(size_t)K;
    const f16* Bl0 = Wl + (size_t)(n0 + fr)*K + kb;
    const f16* Bl1 = Bl0 + 16*(size_t)K;

    const f16 *Axh0=nullptr, *Axh1=nullptr, *Axl0=nullptr, *Axl1=nullptr;
    const f16 *Ach0, *Ach1, *Acl0, *Acl1;
    bool cat = (!isG2 && i == 0);
    if (isG2) {
        const f16* hh = (const f16*)(ws + (i==0?OFF_HH0 : i==1?OFF_HH1 : i==2?OFF_HH2 : OFF_HH3));
        const f16* hl = (const f16*)(ws + (i==0?OFF_HL0 : i==1?OFF_HL1 : i==2?OFF_HL2 : OFF_HL3));
        Ach0 = hh + (size_t)m0*K + kb;  Ach1 = hh + (size_t)m1*K + kb;
        Acl0 = hl + (size_t)m0*K + kb;  Acl1 = hl + (size_t)m1*K + kb;
    } else {
        const f16* ch = (const f16*)(ws + OFF_CTXH);
        const f16* cl = (const f16*)(ws + OFF_CTXL);
        int coff = cat ? 0 : i*256;
        Ach0 = ch + (size_t)m0*1024 + coff + kb;  Ach1 = ch + (size_t)m1*1024 + coff + kb;
        Acl0 = cl + (size_t)m0*1024 + coff + kb;  Acl1 = cl + (size_t)m1*1024 + coff + kb;
        if (cat) {
            const f16* xh = (const f16*)(ws + OFF_XH);
            const f16* xl = (const f16*)(ws + OFF_XL);
            Axh0 = xh + ((size_t)m0*256 + t)*128 + kb;  Axh1 = xh + ((size_t)m1*256 + t)*128 + kb;
            Axl0 = xl + ((size_t)m0*256 + t)*128 + kb;  Axl1 = xl + ((size_t)m1*256 + t)*128 + kb;
        }
    }

    f32x4 hh[2][2] = {}, cr[2][2] = {};
    // pass 1: W_hi  -> hh += A_hi @ W_hi ; cr += A_lo' @ W_hi
    for (int k = 0; k < K; k += 32) {
        const f16 *ph0, *ph1, *pl0, *pl1;
        if (cat && k < 128) { ph0 = Axh0 + k; ph1 = Axh1 + k; pl0 = Axl0 + k; pl1 = Axl1 + k; }
        else { int kc = cat ? k - 128 : k; ph0 = Ach0 + kc; ph1 = Ach1 + kc; pl0 = Acl0 + kc; pl1 = Acl1 + kc; }
        f16x8 ah0 = ld8h(ph0), ah1 = ld8h(ph1), al0 = ld8h(pl0), al1 = ld8h(pl1);
        f16x8 b0 = ld8h(Bh0 + k), b1 = ld8h(Bh1 + k);
        hh[0][0] = __builtin_amdgcn_mfma_f32_16x16x32_f16(ah0, b0, hh[0][0], 0, 0, 0);
        hh[0][1] = __builtin_amdgcn_mfma_f32_16x16x32_f16(ah0, b1, hh[0][1], 0, 0, 0);
        hh[1][0] = __builtin_amdgcn_mfma_f32_16x16x32_f16(ah1, b0, hh[1][0], 0, 0, 0);
        hh[1][1] = __builtin_amdgcn_mfma_f32_16x16x32_f16(ah1, b1, hh[1][1], 0, 0, 0);
        cr[0][0] = __builtin_amdgcn_mfma_f32_16x16x32_f16(al0, b0, cr[0][0], 0, 0, 0);
        cr[0][1] = __builtin_amdgcn_mfma_f32_16x16x32_f16(al0, b1, cr[0][1], 0, 0, 0);
        cr[1][0] = __builtin_amdgcn_mfma_f32_16x16x32_f16(al1, b0, cr[1][0], 0, 0, 0);
        cr[1][1] = __builtin_amdgcn_mfma_f32_16x16x32_f16(al1, b1, cr[1][1], 0, 0, 0);
    }
    // pass 2: W_lo' -> cr += A_hi @ W_lo'
    for (int k = 0; k < K; k += 32) {
        const f16 *ph0, *ph1;
        if (cat && k < 128) { ph0 = Axh0 + k; ph1 = Axh1 + k; }
        else { int kc = cat ? k - 128 : k; ph0 = Ach0 + kc; ph1 = Ach1 + kc; }
        f16x8 ah0 = ld8h(ph0), ah1 = ld8h(ph1);
        f16x8 b0 = ld8h(Bl0 + k), b1 = ld8h(Bl1 + k);
        cr[0][0] = __builtin_amdgcn_mfma_f32_16x16x32_f16(ah0, b0, cr[0][0], 0, 0, 0);
        cr[0][1] = __builtin_amdgcn_mfma_f32_16x16x32_f16(ah0, b1, cr[0][1], 0, 0, 0);
        cr[1][0] = __builtin_amdgcn_mfma_f32_16x16x32_f16(ah1, b0, cr[1][0], 0, 0, 0);
        cr[1][1] = __builtin_amdgcn_mfma_f32_16x16x32_f16(ah1, b1, cr[1][1], 0, 0, 0);
    }
    int drow = wv*32 + (lane >> 4)*4;
    int dcol = n0 + fr;
    #pragma unroll
    for (int mi = 0; mi < 2; ++mi)
        #pragma unroll
        for (int f = 0; f < 2; ++f)
            #pragma unroll
            for (int rr = 0; rr < 4; ++rr)
                Gout[(size_t)(drow + mi*16 + rr)*N3 + dcol + f*16]
                    = hh[mi][f][rr] + cr[mi][f][rr]*(1.0f/4096.0f);
}

// ---------------- step kernel 3: GRU elementwise ----------------
__global__ __launch_bounds__(256) void k_gru(char* ws,
    const float* __restrict__ bih0, const float* __restrict__ bih1,
    const float* __restrict__ bih2, const float* __restrict__ bih3,
    const float* __restrict__ bhh0, const float* __restrict__ bhh1,
    const float* __restrict__ bhh2, const float* __restrict__ bhh3,
    float* __restrict__ out, int t)
{
    int gid = blockIdx.x*256 + threadIdx.x;
    if (gid >= 128*4224) return;
    int m = gid / 4224;
    int col = gid % 4224;
    int i = (col < 3072) ? (col >> 10) : 3;
    int j = (col < 3072) ? (col & 1023) : (col - 3072);
    int H = (i == 3) ? 1152 : 1024;
    int N3 = 3*H;
    size_t goff = moff_g(i) + (size_t)m*N3;
    const float* g1 = (const float*)(ws + OFF_G1) + goff;
    const float* g2 = (const float*)(ws + OFF_G2) + goff;
    const float* bih = (i==0?bih0 : i==1?bih1 : i==2?bih2 : bih3);
    const float* bhh = (i==0?bhh0 : i==1?bhh1 : i==2?bhh2 : bhh3);
    float ir  = g1[j]       + bih[j];
    float iz  = g1[H + j]   + bih[H + j];
    float in_ = g1[2*H + j] + bih[2*H + j];
    float hr  = g2[j]       + bhh[j];
    float hz  = g2[H + j]   + bhh[H + j];
    float hn  = g2[2*H + j] + bhh[2*H + j];
    float rg = 1.f / (1.f + expf(-(ir + hr)));
    float zg = 1.f / (1.f + expf(-(iz + hz)));
    float ng = tanhf(in_ + rg * hn);
    float* hf = (float*)(ws + (i==0?OFF_HF0 : i==1?OFF_HF1 : i==2?OFF_HF2 : OFF_HF3));
    f16* hh = (f16*)(ws + (i==0?OFF_HH0 : i==1?OFF_HH1 : i==2?OFF_HH2 : OFF_HH3));
    f16* hl = (f16*)(ws + (i==0?OFF_HL0 : i==1?OFF_HL1 : i==2?OFF_HL2 : OFF_HL3));
    float hp = hf[(size_t)m*H + j];
    float hnew = (1.f - zg)*ng + zg*hp;
    hf[(size_t)m*H + j] = hnew;
    fsplit(hnew, &hh[(size_t)m*H + j], &hl[(size_t)m*H + j]);
    f16* cenh = (f16*)(ws + OFF_CENH);
    f16* cenl = (f16*)(ws + OFF_CENL);
    if (i < 3) {
        size_t ci = (size_t)m*4096 + i*1024 + j;
        fsplit(hnew, &cenh[ci], &cenl[ci]);
    } else if (j >= 128) {
        size_t ci = (size_t)m*4096 + 3072 + (j - 128);
        fsplit(hnew, &cenh[ci], &cenl[ci]);
    } else {
        out[((size_t)m*256 + t)*128 + j] = hnew;
    }
}

// ---------------- host ----------------
extern "C" void kernel_launch(void* const* d_in, const int* in_sizes, int n_in,
                              void* d_out, int out_size, void* d_ws, size_t ws_size,
                              hipStream_t stream)
{
    char* ws = (char*)d_ws;
    const float* inp   = (const float*)d_in[0];
    const float* cini  = (const float*)d_in[1];
    const float* mini  = (const float*)d_in[2];
    const float* mlast = (const float*)d_in[3];
    const float *pm[4], *wih[4], *whh[4], *bih[4], *bhh[4];
    for (int i = 0; i < 4; ++i) {
        pm[i]  = (const float*)d_in[4 + 5*i];
        wih[i] = (const float*)d_in[5 + 5*i];
        whh[i] = (const float*)d_in[6 + 5*i];
        bih[i] = (const float*)d_in[7 + 5*i];
        bhh[i] = (const float*)d_in[8 + 5*i];
    }
    float* out = (float*)d_out;

    // prep: fp16 hi/lo splits + transposes + state init
    k_split_n<<<16384, 256, 0, stream>>>(inp, (f16*)(ws+OFF_XH), (f16*)(ws+OFF_XL), (int)NXE);
    k_pmt_split<<<16384, 256, 0, stream>>>(pm[0], pm[1], pm[2], pm[3],
                                           (f16*)(ws+OFF_PMH), (f16*)(ws+OFF_PML));
    k_split_n<<<4608, 256, 0, stream>>>(wih[0], (f16*)(ws+OFF_WIHH0), (f16*)(ws+OFF_WIHL0), (int)NWIH0);
    k_split_n<<<3072, 256, 0, stream>>>(wih[1], (f16*)(ws+OFF_WIHH1), (f16*)(ws+OFF_WIHL1), (int)NWIH12);
    k_split_n<<<3072, 256, 0, stream>>>(wih[2], (f16*)(ws+OFF_WIHH2), (f16*)(ws+OFF_WIHL2), (int)NWIH12);
    k_split_n<<<3456, 256, 0, stream>>>(wih[3], (f16*)(ws+OFF_WIHH3), (f16*)(ws+OFF_WIHL3), (int)NWIH3);
    k_split_n<<<12288, 256, 0, stream>>>(whh[0], (f16*)(ws+OFF_WHHH0), (f16*)(ws+OFF_WHHL0), (int)NWHH012);
    k_split_n<<<12288, 256, 0, stream>>>(whh[1], (f16*)(ws+OFF_WHHH1), (f16*)(ws+OFF_WHHL1), (int)NWHH012);
    k_split_n<<<12288, 256, 0, stream>>>(whh[2], (f16*)(ws+OFF_WHHH2), (f16*)(ws+OFF_WHHL2), (int)NWHH012);
    k_split_n<<<15552, 256, 0, stream>>>(whh[3], (f16*)(ws+OFF_WHHH3), (f16*)(ws+OFF_WHHL3), (int)NWHH3);
    k_init_cen<<<2048, 256, 0, stream>>>(cini, ws);
    k_init_mod<<<1536, 256, 0, stream>>>(mini, ws);
    k_init_last<<<576, 256, 0, stream>>>(mlast, ws);

    for (int t = 0; t < 256; ++t) {
        k_ctx<<<256, 256, 0, stream>>>(ws);
        k_gates<<<792, 256, 0, stream>>>(ws, t);
        k_gru<<<2112, 256, 0, stream>>>(ws,
            bih[0], bih[1], bih[2], bih[3],
            bhh[0], bhh[1], bhh[2], bhh[3],
            out, t);
    }
    (void)in_sizes; (void)n_in; (void)out_size; (void)ws_size; (void)WS_NEED;
}